// Round 6
// baseline (146.213 us; speedup 1.0000x reference)
//
#include <hip/hip_runtime.h>
#include <stdint.h>
#include <stddef.h>

#define SEQ 2048
#define NH 16
#define HD 64
#define NB 2
#define HID 1024

typedef short bf16x8 __attribute__((ext_vector_type(8)));
typedef float f32x4 __attribute__((ext_vector_type(4)));
typedef float f32x16 __attribute__((ext_vector_type(16)));
typedef unsigned u32x2 __attribute__((ext_vector_type(2)));

__device__ __forceinline__ unsigned short f2bf(float f) {
  unsigned u = __float_as_uint(f);
  u += 0x7fffu + ((u >> 16) & 1u);
  return (unsigned short)(u >> 16);
}

__device__ __forceinline__ unsigned cvtpk(float lo, float hi) {
  unsigned d;
  asm("v_cvt_pk_bf16_f32 %0, %1, %2" : "=v"(d) : "v"(lo), "v"(hi));
  return d;
}

__device__ __forceinline__ void load_lds16(const void* g, void* l) {
  __builtin_amdgcn_global_load_lds(
      (const __attribute__((address_space(1))) unsigned int*)g,
      (__attribute__((address_space(3))) unsigned int*)l, 16, 0, 0);
}

// ---------------- fp32 -> bf16 conversion of x and the 4 weight matrices ----
__global__ __launch_bounds__(256) void convert_all(
    const float* __restrict__ x, const float* __restrict__ wq,
    const float* __restrict__ wk, const float* __restrict__ wv,
    const float* __restrict__ wo, unsigned short* __restrict__ dst) {
  long i = ((long)blockIdx.x * 256 + threadIdx.x) * 4;
  const float* src; long off;
  if (i < 4194304L)      { src = x;  off = i; }
  else if (i < 5242880L) { src = wq; off = i - 4194304L; }
  else if (i < 6291456L) { src = wk; off = i - 5242880L; }
  else if (i < 7340032L) { src = wv; off = i - 6291456L; }
  else                   { src = wo; off = i - 7340032L; }
  float4 v = *reinterpret_cast<const float4*>(src + off);
  ushort4 o;
  o.x = f2bf(v.x); o.y = f2bf(v.y); o.z = f2bf(v.z); o.w = f2bf(v.w);
  *reinterpret_cast<ushort4*>(dst + i) = o;
}

// ---------------- mask -> 64x64-block "any zero" map ------------------------
__global__ __launch_bounds__(256) void mask_reduce(const int* __restrict__ mask,
                                                   int* __restrict__ map) {
  const int qb = blockIdx.y, kb = blockIdx.x;
  int bad = 0;
  for (int i = threadIdx.x; i < 4096; i += 256) {
    int qq = i >> 6, kk = i & 63;
    bad |= (mask[(size_t)(qb * 64 + qq) * SEQ + kb * 64 + kk] == 0);
  }
  __shared__ int red[4];
  unsigned long long any = __ballot(bad);
  if ((threadIdx.x & 63) == 0) red[threadIdx.x >> 6] = (any != 0ULL);
  __syncthreads();
  if (threadIdx.x == 0) map[qb * 32 + kb] = red[0] | red[1] | red[2] | red[3];
}

// ---------------- m97-structure GEMM core: C(128x128) = A * B^T --------------
__device__ __forceinline__ void gemm128_core(
    const unsigned short* __restrict__ A, const unsigned short* __restrict__ Bw,
    int m0, int n0, unsigned short* As, unsigned short* Bs, f32x4 acc[4][4]) {
  const int t = threadIdx.x;
  const int lane = t & 63;
  const int r = lane & 15, g = lane >> 4;
  const int wr = (t >> 6) >> 1, wc = (t >> 6) & 1;
  for (int k0 = 0; k0 < HID; k0 += 32) {
#pragma unroll
    for (int i = 0; i < 2; ++i) {
      int c = i * 256 + t;           // 512 16B-chunks per 128x32 tile
      int row = c >> 2, sl = (c & 3) << 3;
      load_lds16(A + (size_t)(m0 + row) * HID + k0 + sl, As + c * 8);
      load_lds16(Bw + (size_t)(n0 + row) * HID + k0 + sl, Bs + c * 8);
    }
    __syncthreads();
    bf16x8 af[4], bf[4];
#pragma unroll
    for (int mt = 0; mt < 4; ++mt)
      af[mt] = *reinterpret_cast<const bf16x8*>(As + (wr * 64 + mt * 16 + r) * 32 + g * 8);
#pragma unroll
    for (int nt = 0; nt < 4; ++nt)
      bf[nt] = *reinterpret_cast<const bf16x8*>(Bs + (wc * 64 + nt * 16 + r) * 32 + g * 8);
#pragma unroll
    for (int mt = 0; mt < 4; ++mt)
#pragma unroll
      for (int nt = 0; nt < 4; ++nt)
        acc[mt][nt] = __builtin_amdgcn_mfma_f32_16x16x32_bf16(af[mt], bf[nt], acc[mt][nt], 0, 0, 0);
    __syncthreads();
  }
}

// ---------------- fused QKV projection (N = 3072, z = n>>10) -----------------
// Q output pre-scaled by 0.125*log2(e) (attention scale + exp2 folding).
__global__ __launch_bounds__(256) void gemm_qkv(
    const unsigned short* __restrict__ xb, const unsigned short* __restrict__ wb,
    const float* __restrict__ bq, const float* __restrict__ bk,
    const float* __restrict__ bv, unsigned short* __restrict__ Qd,
    unsigned short* __restrict__ Kd, unsigned short* __restrict__ Vt) {
  __shared__ __align__(16) unsigned short As[128 * 32];
  __shared__ __align__(16) unsigned short Bs[128 * 32];
  const int m0 = blockIdx.y * 128, n0 = blockIdx.x * 128;
  const int z = n0 >> 10;  // 128-tile never straddles a weight boundary
  f32x4 zv = {0.f, 0.f, 0.f, 0.f};
  f32x4 acc[4][4];
#pragma unroll
  for (int a = 0; a < 4; ++a)
#pragma unroll
    for (int c = 0; c < 4; ++c) acc[a][c] = zv;
  gemm128_core(xb, wb, m0, n0, As, Bs, acc);
  const int t = threadIdx.x, lane = t & 63;
  const int r = lane & 15, g = lane >> 4;
  const int wr = (t >> 6) >> 1, wc = (t >> 6) & 1;
  const float* bias = (z == 0) ? bq : (z == 1) ? bk : bv;
  const float scl = (z == 0) ? 0.125f * 1.44269504f : 1.0f;
#pragma unroll
  for (int nt = 0; nt < 4; ++nt) {
    int n = n0 + wc * 64 + nt * 16 + r;
    int nn = n & 1023;
    float bb = bias[nn];
    int h = nn >> 6, d = nn & 63;
#pragma unroll
    for (int mt = 0; mt < 4; ++mt) {
#pragma unroll
      for (int i = 0; i < 4; ++i) {
        int m = m0 + wr * 64 + mt * 16 + g * 4 + i;
        int b = m >> 11, s = m & 2047;
        int bh = b * NH + h;
        unsigned short val = f2bf((acc[mt][nt][i] + bb) * scl);
        if (z == 0)      Qd[((size_t)bh * SEQ + s) * HD + d] = val;
        else if (z == 1) Kd[((size_t)bh * SEQ + s) * HD + d] = val;
        else             Vt[((size_t)bh * HD + d) * SEQ + s] = val;
      }
    }
  }
}

// ---------------- output projection: fp32 out + bias ------------------------
__global__ __launch_bounds__(256) void gemm_out(
    const unsigned short* __restrict__ Ob, const unsigned short* __restrict__ Wob,
    const float* __restrict__ bo, float* __restrict__ out) {
  __shared__ __align__(16) unsigned short As[128 * 32];
  __shared__ __align__(16) unsigned short Bs[128 * 32];
  const int m0 = blockIdx.y * 128, n0 = blockIdx.x * 128;
  f32x4 zv = {0.f, 0.f, 0.f, 0.f};
  f32x4 acc[4][4];
#pragma unroll
  for (int a = 0; a < 4; ++a)
#pragma unroll
    for (int c = 0; c < 4; ++c) acc[a][c] = zv;
  gemm128_core(Ob, Wob, m0, n0, As, Bs, acc);
  const int t = threadIdx.x, lane = t & 63;
  const int r = lane & 15, g = lane >> 4;
  const int wr = (t >> 6) >> 1, wc = (t >> 6) & 1;
#pragma unroll
  for (int nt = 0; nt < 4; ++nt) {
    int n = n0 + wc * 64 + nt * 16 + r;
    float bb = bo[n];
#pragma unroll
    for (int mt = 0; mt < 4; ++mt) {
#pragma unroll
      for (int i = 0; i < 4; ++i) {
        int m = m0 + wr * 64 + mt * 16 + g * 4 + i;
        out[(size_t)m * HID + n] = acc[mt][nt][i] + bb;
      }
    }
  }
}

// ---------------- flash attention v5: 2-tile ILP braid ----------------------
// grid (S/128, BH), 256 threads = 4 waves; wave owns 32 queries (swapped-QK,
// 32x32x16 MFMA, in-register softmax in exp2 domain). K-tiles processed in
// PAIRS: QK(A);QK(B) issued back-to-back, then softmax(A) on VALU overlaps
// QK(B) in the matrix pipe; PV(A) overlaps softmax(B). 4 LDS buffers (64KB),
// one vmcnt(0)+barrier per pair. Mask gate via pre-ballot'd SGPR mapmask.
__global__ __launch_bounds__(256, 2) void flash_attn(
    const unsigned short* __restrict__ Q, const unsigned short* __restrict__ K,
    const unsigned short* __restrict__ Vt, const int* __restrict__ map,
    const int* __restrict__ mask, unsigned short* __restrict__ O) {
  __shared__ __align__(16) unsigned short Ks[4][64][64];
  __shared__ __align__(16) unsigned short Vs[4][64][64];
  const int bh = blockIdx.y;
  const int t = threadIdx.x;
  const int lane = t & 63, wave = t >> 6;
  const int q = lane & 31, hi = lane >> 5;
  const int q0w = blockIdx.x * 128 + wave * 32;
  const unsigned short* Qb = Q + (size_t)bh * SEQ * HD;
  const unsigned short* Kb = K + (size_t)bh * SEQ * HD;
  const unsigned short* Vb = Vt + (size_t)bh * HD * SEQ;

  // Q as B-operand fragments: lane holds Q[q0w+q][dd*16 + hi*8 + j]
  bf16x8 qfr[4];
#pragma unroll
  for (int dd = 0; dd < 4; ++dd)
    qfr[dd] = *reinterpret_cast<const bf16x8*>(
        Qb + (size_t)(q0w + q) * HD + dd * 16 + hi * 8);

  // mask tile map for this q-row, as a wave-uniform bitmask (bit kb>>6)
  const unsigned long long mapmask =
      __ballot(map[(q0w >> 6) * 32 + (lane & 31)] != 0);

  bf16x8 onesf;
#pragma unroll
  for (int j = 0; j < 8; ++j) onesf[j] = (short)0x3F80;  // bf16 1.0

  f32x16 zv16 = {0.f};
  f32x16 oacc[2];
  oacc[0] = zv16; oacc[1] = zv16;
  float mrun = -1e30f, lrun = 0.f;

  // staging: 256 threads cover rows {srow, srow+32} x 8 16B-slots.
  const int srow = t >> 3;
  const int sslot = t & 7;

#define STAGE_K(kbase, buf) do {                                            \
    int c0 = sslot ^ (srow & 7);                                            \
    load_lds16(Kb + (size_t)((kbase) + srow) * HD + c0 * 8,                 \
               &Ks[buf][srow][sslot * 8]);                                  \
    load_lds16(Kb + (size_t)((kbase) + 32 + srow) * HD + c0 * 8,            \
               &Ks[buf][32 + srow][sslot * 8]);                             \
  } while (0)
#define STAGE_V(kbase, buf) do {                                            \
    int c0 = sslot ^ (srow & 7);                                            \
    load_lds16(Vb + (size_t)srow * SEQ + (kbase) + c0 * 8,                  \
               &Vs[buf][srow][sslot * 8]);                                  \
    load_lds16(Vb + (size_t)(32 + srow) * SEQ + (kbase) + c0 * 8,           \
               &Vs[buf][32 + srow][sslot * 8]);                             \
  } while (0)
#define KFR(buf, row, s) \
  (*reinterpret_cast<const bf16x8*>(&Ks[buf][row][(((s) ^ ((row) & 7)) << 3)]))
#define VFR(buf, row, s) \
  (*reinterpret_cast<const bf16x8*>(&Vs[buf][row][(((s) ^ ((row) & 7)) << 3)]))

// QK^T for one tile from LDS buffer `buf` into sacc[2]
#define QK_TILE(sacc, buf) do {                                             \
    __builtin_amdgcn_s_setprio(1);                                          \
    _Pragma("unroll")                                                       \
    for (int ks = 0; ks < 2; ++ks) {                                        \
      int row = ks * 32 + q;                                                \
      _Pragma("unroll")                                                     \
      for (int dd = 0; dd < 4; ++dd) {                                      \
        bf16x8 kf = KFR(buf, row, dd * 2 + hi);                             \
        sacc[ks] = __builtin_amdgcn_mfma_f32_32x32x16_bf16(kf, qfr[dd],     \
                                                           sacc[ks], 0, 0, 0);\
      }                                                                     \
    }                                                                       \
    __builtin_amdgcn_s_setprio(0);                                          \
  } while (0)

// softmax (exp2 domain, in place) + pack to bf16 fragments + PV + row-sum
#define SM_PV(sacc, buf, kb_t) do {                                         \
    if ((mapmask >> ((kb_t) >> 6)) & 1) {                                   \
      _Pragma("unroll")                                                     \
      for (int ks = 0; ks < 2; ++ks)                                        \
        _Pragma("unroll")                                                   \
        for (int rg = 0; rg < 16; ++rg) {                                   \
          int kl = ks * 32 + (rg & 3) + 8 * (rg >> 2) + 4 * hi;             \
          if (mask[(size_t)(q0w + q) * SEQ + (kb_t) + kl] == 0)             \
            sacc[ks][rg] = -__builtin_inff();                               \
        }                                                                   \
    }                                                                       \
    float t16[16];                                                          \
    _Pragma("unroll")                                                       \
    for (int j = 0; j < 16; ++j) t16[j] = fmaxf(sacc[0][j], sacc[1][j]);    \
    float t4[4];                                                            \
    _Pragma("unroll")                                                       \
    for (int j = 0; j < 4; ++j)                                             \
      t4[j] = fmaxf(fmaxf(t16[j], t16[j + 4]), fmaxf(t16[j + 8], t16[j + 12]));\
    float pmax = fmaxf(fmaxf(t4[0], t4[1]), fmaxf(t4[2], t4[3]));           \
    pmax = fmaxf(pmax, __shfl_xor(pmax, 32, 64));                           \
    if (!__all(pmax <= mrun + 11.5f)) {                                     \
      float mnew = fmaxf(mrun, pmax);                                       \
      float corr = exp2f(mrun - mnew);                                      \
      mrun = mnew;                                                          \
      lrun *= corr;                                                         \
      _Pragma("unroll")                                                     \
      for (int dh = 0; dh < 2; ++dh)                                        \
        _Pragma("unroll")                                                   \
        for (int rg = 0; rg < 16; ++rg) oacc[dh][rg] *= corr;               \
    }                                                                       \
    _Pragma("unroll")                                                       \
    for (int ks = 0; ks < 2; ++ks)                                          \
      _Pragma("unroll")                                                     \
      for (int rg = 0; rg < 16; ++rg)                                       \
        sacc[ks][rg] = exp2f(sacc[ks][rg] - mrun);                          \
    bf16x8 pfrag[4];                                                        \
    _Pragma("unroll")                                                       \
    for (int f = 0; f < 4; ++f) {  /* f = ks*2 + half */                    \
      int ks = f >> 1, b0 = (f & 1) * 8;                                    \
      unsigned w0 = cvtpk(sacc[ks][b0 + 0], sacc[ks][b0 + 1]);              \
      unsigned w1 = cvtpk(sacc[ks][b0 + 2], sacc[ks][b0 + 3]);              \
      unsigned w2 = cvtpk(sacc[ks][b0 + 4], sacc[ks][b0 + 5]);              \
      unsigned w3 = cvtpk(sacc[ks][b0 + 6], sacc[ks][b0 + 7]);              \
      u32x2 s02 = __builtin_amdgcn_permlane32_swap(w0, w2, false, false);   \
      u32x2 s13 = __builtin_amdgcn_permlane32_swap(w1, w3, false, false);   \
      union { unsigned u[4]; bf16x8 v; } fr;                                \
      fr.u[0] = s02[0]; fr.u[1] = s13[0]; fr.u[2] = s02[1]; fr.u[3] = s13[1];\
      pfrag[f] = fr.v;                                                      \
    }                                                                       \
    f32x16 lacc = zv16;                                                     \
    __builtin_amdgcn_s_setprio(1);                                          \
    _Pragma("unroll")                                                       \
    for (int f = 0; f < 4; ++f)                                             \
      lacc = __builtin_amdgcn_mfma_f32_32x32x16_bf16(onesf, pfrag[f], lacc, \
                                                     0, 0, 0);              \
    _Pragma("unroll")                                                       \
    for (int dh = 0; dh < 2; ++dh) {                                        \
      int row = dh * 32 + q;                                                \
      _Pragma("unroll")                                                     \
      for (int f = 0; f < 4; ++f) {                                         \
        bf16x8 vf = VFR(buf, row, f * 2 + hi);                              \
        oacc[dh] = __builtin_amdgcn_mfma_f32_32x32x16_bf16(vf, pfrag[f],    \
                                                           oacc[dh], 0, 0, 0);\
      }                                                                     \
    }                                                                       \
    __builtin_amdgcn_s_setprio(0);                                          \
    lrun += lacc[0];                                                        \
  } while (0)

  STAGE_K(0, 0);
  STAGE_V(0, 0);
  STAGE_K(64, 1);
  STAGE_V(64, 1);
  asm volatile("s_waitcnt vmcnt(0)" ::: "memory");
  __syncthreads();

  for (int kb = 0; kb < SEQ; kb += 128) {
    const int bufA = ((kb >> 7) & 1) * 2;
    const int bufB = bufA + 1;
    // prefetch next pair into the other buffer pair
    if (kb + 128 < SEQ) {
      STAGE_K(kb + 128, bufA ^ 2);
      STAGE_V(kb + 128, bufA ^ 2);
      STAGE_K(kb + 192, bufB ^ 2);
      STAGE_V(kb + 192, bufB ^ 2);
    }
    // issue both QK tiles back-to-back, then braid softmax/PV
    f32x16 sA[2]; sA[0] = zv16; sA[1] = zv16;
    f32x16 sB[2]; sB[0] = zv16; sB[1] = zv16;
    QK_TILE(sA, bufA);
    QK_TILE(sB, bufB);
    SM_PV(sA, bufA, kb);
    SM_PV(sB, bufB, kb + 64);
    asm volatile("s_waitcnt vmcnt(0)" ::: "memory");
    __syncthreads();
  }

  const float rl = 1.0f / lrun;
  const int b = bh >> 4, h = bh & 15;
  unsigned short* orow = O + (size_t)(b * SEQ + q0w + q) * HID + h * HD;
#pragma unroll
  for (int dh = 0; dh < 2; ++dh)
#pragma unroll
    for (int r2 = 0; r2 < 4; ++r2) {
      float v0 = oacc[dh][r2 * 4 + 0] * rl;
      float v1 = oacc[dh][r2 * 4 + 1] * rl;
      float v2 = oacc[dh][r2 * 4 + 2] * rl;
      float v3 = oacc[dh][r2 * 4 + 3] * rl;
      u32x2 pk;
      pk[0] = (unsigned)f2bf(v0) | ((unsigned)f2bf(v1) << 16);
      pk[1] = (unsigned)f2bf(v2) | ((unsigned)f2bf(v3) << 16);
      *reinterpret_cast<u32x2*>(orow + dh * 32 + r2 * 8 + hi * 4) = pk;
    }
#undef STAGE_K
#undef STAGE_V
#undef KFR
#undef VFR
#undef QK_TILE
#undef SM_PV
}

// ---------------- launch -----------------------------------------------------
extern "C" void kernel_launch(void* const* d_in, const int* in_sizes, int n_in,
                              void* d_out, int out_size, void* d_ws, size_t ws_size,
                              hipStream_t stream) {
  const float* x    = (const float*)d_in[0];
  const int*   mask = (const int*)d_in[1];
  const float* Wq   = (const float*)d_in[2];
  const float* bq   = (const float*)d_in[3];
  const float* Wk   = (const float*)d_in[4];
  const float* bk   = (const float*)d_in[5];
  const float* Wv   = (const float*)d_in[6];
  const float* bv   = (const float*)d_in[7];
  const float* Wo   = (const float*)d_in[8];
  const float* bo   = (const float*)d_in[9];
  float* out = (float*)d_out;

  unsigned short* ws = (unsigned short*)d_ws;
  unsigned short* xb = ws;                      // 4194304 bf16
  unsigned short* wb = ws + 4194304;            // 4 x 1048576 (Wq,Wk,Wv,Wo)
  unsigned short* Qd = ws + 8388608;            // [32][2048][64] (pre-scaled)
  unsigned short* Kd = ws + 12582912;           // [32][2048][64]
  unsigned short* Vt = ws + 16777216;           // [32][64][2048]
  unsigned short* Ob = ws + 20971520;           // [4096][1024]
  int* map = (int*)(ws + 25165824);             // [32][32]

  convert_all<<<8192, 256, 0, stream>>>(x, Wq, Wk, Wv, Wo, ws);
  mask_reduce<<<dim3(32, 32), 256, 0, stream>>>(mask, map);
  gemm_qkv<<<dim3(24, 32), 256, 0, stream>>>(xb, wb, bq, bk, bv, Qd, Kd, Vt);
  flash_attn<<<dim3(16, 32), 256, 0, stream>>>(Qd, Kd, Vt, map, mask, Ob);
  gemm_out<<<dim3(8, 32), 256, 0, stream>>>(Ob, wb + 3 * 1048576, bo, out);
}